// Round 1
// baseline (92.513 us; speedup 1.0000x reference)
//
#include <hip/hip_runtime.h>

// GMM NLL loss: B=4, N=4096, M=4096, scalar output (mean nll).
// Strategy: log2-domain evaluation, no max-subtraction (range-safe, see notes),
// n-dim split across blocks with float atomics into d_ws (B*M floats = 64 KB).

constexpr int Bc = 4, Nc = 4096, Mc = 4096;
constexpr int NC = 64;               // n-chunk per block
constexpr int TM = 4;                // m values per thread
constexpr int THREADS = 256;
constexpr int MTILE = THREADS * TM;  // 1024 m per block

#define EPS 1e-8f
constexpr float LOG2E   = 1.4426950408889634f;
constexpr float LN2     = 0.6931471805599453f;
constexpr float LOG_2PI = 1.8378762043478343f;   // ln(2*3.14159) -- matches reference constant
constexpr float K_CONST = -1.5f * LOG_2PI * LOG2E; // fold -1.5*LOG_2PI into log2-domain k

__global__ __launch_bounds__(THREADS) void gmm_partial(
    const float* __restrict__ pred_xyz,   // (B,N,3)
    const float* __restrict__ pred_sigma, // (B,N,2)
    const float* __restrict__ target,    // (B,M,3)
    float* __restrict__ sums)            // (B,M) accumulators, pre-zeroed
{
    __shared__ float4 lds[NC * 2]; // per n: [px,py,pz,k2], [a2,c2,-,-]

    const int nck = blockIdx.x;
    const int mt  = blockIdx.y;
    const int b   = blockIdx.z;
    const int tid = threadIdx.x;
    const int n0  = nck * NC;

    // On-the-fly per-n transform into LDS (64 lanes active; cost amortized over 1024 m)
    if (tid < NC) {
        const int n = n0 + tid;
        const float* pp = pred_xyz + ((size_t)b * Nc + n) * 3;
        const float px = pp[0], py = pp[1], pz = pp[2];
        const float* ps = pred_sigma + ((size_t)b * Nc + n) * 2;
        const float sxy = ps[0] + EPS;
        const float sz  = ps[1] + EPS;
        // log2-domain coefficients: lp2 = k2 + a2*dist_xy + c2*dist_z ; prob = 2^lp2
        const float a2 = -0.5f * LOG2E * __builtin_amdgcn_rcpf(sxy);
        const float c2 = -0.5f * LOG2E * __builtin_amdgcn_rcpf(sz);
        const float k2 = -__builtin_amdgcn_logf(sxy)            // v_log_f32 = log2
                         - 0.5f * __builtin_amdgcn_logf(sz)
                         + K_CONST;
        lds[2 * tid]     = make_float4(px, py, pz, k2);
        lds[2 * tid + 1] = make_float4(a2, c2, 0.f, 0.f);
    }
    __syncthreads();

    // Per-thread targets in registers (fixed for whole block)
    float tx[TM], ty[TM], tz[TM], acc[TM];
    const int m0 = mt * MTILE;
#pragma unroll
    for (int j = 0; j < TM; ++j) {
        const int m = m0 + j * THREADS + tid;
        const float* tp = target + ((size_t)b * Mc + m) * 3;
        tx[j] = tp[0]; ty[j] = tp[1]; tz[j] = tp[2];
        acc[j] = 0.f;
    }

    // Main loop: wave-uniform LDS broadcast reads, 4 independent exp chains per n
    for (int i = 0; i < NC; ++i) {
        const float4 r0 = lds[2 * i];       // px,py,pz,k2
        const float4 r1 = lds[2 * i + 1];   // a2,c2
#pragma unroll
        for (int j = 0; j < TM; ++j) {
            const float dx  = r0.x - tx[j];
            const float dy  = r0.y - ty[j];
            const float dz  = r0.z - tz[j];
            const float dxy = fmaf(dy, dy, dx * dx);
            const float dzz = dz * dz;
            const float lp  = fmaf(r1.y, dzz, fmaf(r1.x, dxy, r0.w));
            acc[j] += __builtin_amdgcn_exp2f(lp);
        }
    }

#pragma unroll
    for (int j = 0; j < TM; ++j) {
        const int m = m0 + j * THREADS + tid;
        atomicAdd(&sums[(size_t)b * Mc + m], acc[j]);
    }
}

__global__ __launch_bounds__(256) void gmm_finalize(
    const float* __restrict__ sums, float* __restrict__ out)
{
    float local = 0.f;
    for (int i = threadIdx.x; i < Bc * Mc; i += 256) {
        local += __builtin_amdgcn_logf(sums[i]);   // log2(sum)
    }
    // wave reduce (width 64)
#pragma unroll
    for (int off = 32; off > 0; off >>= 1) {
        local += __shfl_down(local, off, 64);
    }
    __shared__ float w[4];
    const int wave = threadIdx.x >> 6;
    if ((threadIdx.x & 63) == 0) w[wave] = local;
    __syncthreads();
    if (threadIdx.x == 0) {
        const float t = w[0] + w[1] + w[2] + w[3];
        // nll_i = -ln2 * log2(sum_i); mean over B*M
        out[0] = -LN2 * t / (float)(Bc * Mc);
    }
}

extern "C" void kernel_launch(void* const* d_in, const int* in_sizes, int n_in,
                              void* d_out, int out_size, void* d_ws, size_t ws_size,
                              hipStream_t stream) {
    const float* pred_xyz   = (const float*)d_in[0];
    const float* pred_sigma = (const float*)d_in[1];
    const float* target     = (const float*)d_in[2];
    float* out  = (float*)d_out;
    float* sums = (float*)d_ws;   // B*M floats = 64 KB

    hipMemsetAsync(sums, 0, (size_t)Bc * Mc * sizeof(float), stream);

    dim3 grid(Nc / NC, Mc / MTILE, Bc);   // (64, 4, 4) = 1024 blocks
    gmm_partial<<<grid, THREADS, 0, stream>>>(pred_xyz, pred_sigma, target, sums);
    gmm_finalize<<<1, 256, 0, stream>>>(sums, out);
}

// Round 2
// 77.028 us; speedup vs baseline: 1.2010x; 1.2010x over previous
//
#include <hip/hip_runtime.h>

// GMM NLL loss: B=4, N=4096, M=4096, scalar output (mean nll).
// Log2-domain, no max-subtraction (range-safe: lp2 in ~[-40,+20], sum*4096 << f32 max).
// Rank-6 expansion: lp = K2(n) + A(n)*txy2 + C(n)*tz2 + Bx(n)*tx + By(n)*ty + Cz(n)*tz
//   => 5 fma + exp2 + add per (n,m) pair.
// n-split across blocks, float atomics into d_ws (B*M floats = 64 KB); parallel finalize.

constexpr int Bc = 4, Nc = 4096, Mc = 4096;
constexpr int NC = 64;               // n-chunk per block
constexpr int TM = 8;                // m values per thread
constexpr int THREADS = 256;
constexpr int MTILE = THREADS * TM;  // 2048 m per block

#define EPS 1e-8f
constexpr float LOG2E   = 1.4426950408889634f;
constexpr float LN2     = 0.6931471805599453f;
constexpr float LOG_2PI = 1.8378762043478343f;   // ln(2*3.14159), matches reference
constexpr float K_CONST = -1.5f * LOG_2PI * LOG2E;

__global__ __launch_bounds__(THREADS) void gmm_partial(
    const float* __restrict__ pred_xyz,   // (B,N,3)
    const float* __restrict__ pred_sigma, // (B,N,2)
    const float* __restrict__ target,     // (B,M,3)
    float* __restrict__ sums)             // (B,M) accumulators, pre-zeroed
{
    __shared__ float4 lds[NC * 2]; // per n: [K2, A, C, Bx], [By, Cz, -, -]

    const int nck = blockIdx.x;
    const int mt  = blockIdx.y;
    const int b   = blockIdx.z;
    const int tid = threadIdx.x;
    const int n0  = nck * NC;

    // Per-n transform into LDS (64 lanes active; amortized over 2048 m)
    if (tid < NC) {
        const int n = n0 + tid;
        const float* pp = pred_xyz + ((size_t)b * Nc + n) * 3;
        const float px = pp[0], py = pp[1], pz = pp[2];
        const float* ps = pred_sigma + ((size_t)b * Nc + n) * 2;
        const float sxy = ps[0] + EPS;
        const float sz  = ps[1] + EPS;
        const float A  = -0.5f * LOG2E * __builtin_amdgcn_rcpf(sxy);
        const float C  = -0.5f * LOG2E * __builtin_amdgcn_rcpf(sz);
        const float k2 = -__builtin_amdgcn_logf(sxy)          // v_log_f32 = log2
                         - 0.5f * __builtin_amdgcn_logf(sz)
                         + K_CONST;
        const float K2 = k2 + A * (px * px + py * py) + C * (pz * pz);
        const float Bx = -2.f * A * px;
        const float By = -2.f * A * py;
        const float Cz = -2.f * C * pz;
        lds[2 * tid]     = make_float4(K2, A, C, Bx);
        lds[2 * tid + 1] = make_float4(By, Cz, 0.f, 0.f);
    }
    __syncthreads();

    // Per-thread target registers (fixed for whole block)
    float tx[TM], ty[TM], tz[TM], txy2[TM], tz2[TM], acc[TM];
    const int m0 = mt * MTILE;
#pragma unroll
    for (int j = 0; j < TM; ++j) {
        const int m = m0 + j * THREADS + tid;
        const float* tp = target + ((size_t)b * Mc + m) * 3;
        tx[j] = tp[0]; ty[j] = tp[1]; tz[j] = tp[2];
        txy2[j] = tx[j] * tx[j] + ty[j] * ty[j];
        tz2[j]  = tz[j] * tz[j];
        acc[j] = 0.f;
    }

    // Main loop: wave-uniform LDS broadcast reads; 8 independent chains per n.
#pragma unroll 4
    for (int i = 0; i < NC; ++i) {
        const float4 r0 = lds[2 * i];       // K2, A, C, Bx
        const float4 r1 = lds[2 * i + 1];   // By, Cz
#pragma unroll
        for (int j = 0; j < TM; ++j) {
            float lp = fmaf(r0.y, txy2[j], r0.x);   // K2 + A*txy2
            lp = fmaf(r0.z, tz2[j], lp);            // + C*tz2
            lp = fmaf(r0.w, tx[j], lp);             // + Bx*tx
            lp = fmaf(r1.x, ty[j], lp);             // + By*ty
            lp = fmaf(r1.y, tz[j], lp);             // + Cz*tz
            acc[j] += __builtin_amdgcn_exp2f(lp);
        }
    }

#pragma unroll
    for (int j = 0; j < TM; ++j) {
        const int m = m0 + j * THREADS + tid;
        atomicAdd(&sums[(size_t)b * Mc + m], acc[j]);
    }
}

// Parallel finalize: 64 blocks x 256 threads, 1 element each; per-block atomicAdd.
__global__ __launch_bounds__(256) void gmm_finalize(
    const float* __restrict__ sums, float* __restrict__ out)
{
    const int i = blockIdx.x * 256 + threadIdx.x;
    float local = __builtin_amdgcn_logf(sums[i]);   // log2(sum_i)
#pragma unroll
    for (int off = 32; off > 0; off >>= 1) {
        local += __shfl_down(local, off, 64);
    }
    __shared__ float w[4];
    const int wave = threadIdx.x >> 6;
    if ((threadIdx.x & 63) == 0) w[wave] = local;
    __syncthreads();
    if (threadIdx.x == 0) {
        const float t = w[0] + w[1] + w[2] + w[3];
        // nll_i = -ln2 * log2(sum_i); mean over B*M
        atomicAdd(out, -LN2 / (float)(Bc * Mc) * t);
    }
}

extern "C" void kernel_launch(void* const* d_in, const int* in_sizes, int n_in,
                              void* d_out, int out_size, void* d_ws, size_t ws_size,
                              hipStream_t stream) {
    const float* pred_xyz   = (const float*)d_in[0];
    const float* pred_sigma = (const float*)d_in[1];
    const float* target     = (const float*)d_in[2];
    float* out  = (float*)d_out;
    float* sums = (float*)d_ws;   // B*M floats = 64 KB

    hipMemsetAsync(sums, 0, (size_t)Bc * Mc * sizeof(float), stream);
    hipMemsetAsync(out, 0, sizeof(float), stream);

    dim3 grid(Nc / NC, Mc / MTILE, Bc);   // (64, 2, 4) = 512 blocks
    gmm_partial<<<grid, THREADS, 0, stream>>>(pred_xyz, pred_sigma, target, sums);
    gmm_finalize<<<Bc * Mc / 256, 256, 0, stream>>>(sums, out);
}